// Round 12
// baseline (62.349 us; speedup 1.0000x reference)
//
#include <hip/hip_runtime.h>
#include <stdint.h>

// CoarseMatching R12:
//  0) cvt_x1_kernel: x1 -> pre-swizzled hi/lo bf16 chunk images (as R11)
//     cvt_pos_kernel: pos1 -> packed float4 [px,py,pz,0] image.
//  A) corr_probs_kernel: R11 + x0 B-operand fragments HOISTED to registers
//     (loop-invariant; halves A's LDS reads 128->64 per wave).
//  B) splat_mfma_kernel: R11 + packed float4 pos1 loads (1 load/key vs 3).
#define GRID_NUM 12
#define G3 1728
#define L0V 2048
#define L1V 1024
#define CV 64
#define RT 16               // query rows per block (kernel A)

typedef __attribute__((ext_vector_type(8))) short short8;
typedef __attribute__((ext_vector_type(4))) short short4v;
typedef __attribute__((ext_vector_type(4))) float f32x4;

__device__ __forceinline__ unsigned short f2bf(float f) {
    union { float f; unsigned u; } v; v.f = f;
    unsigned u = v.u;
    u += 0x7fffu + ((u >> 16) & 1u);     // round-to-nearest-even
    return (unsigned short)(u >> 16);
}
__device__ __forceinline__ float bf2f(unsigned short h) {
    union { unsigned u; float f; } v; v.u = ((unsigned)h) << 16;
    return v.f;
}

__device__ __forceinline__ void gload16(const void* g, void* l) {
    __builtin_amdgcn_global_load_lds(
        (const __attribute__((address_space(1))) unsigned int*)(uintptr_t)g,
        (__attribute__((address_space(3))) unsigned int*)(uintptr_t)l,
        16, 0, 0);
}

// ---------------- Kernel 0a: x1 -> pre-swizzled hi/lo bf16 images ----------
__global__ __launch_bounds__(256) void cvt_x1_kernel(
    const float* __restrict__ x1, unsigned short* __restrict__ ximg)
{
    const int g  = blockIdx.x * 256 + threadIdx.x;   // 32768 total
    const int kg = g >> 3;                           // global key (b*1024+key)
    const int j8 = g & 7;
    const int key = kg & 1023;
    const int ch  = key >> 6;
    const int kk  = key & 63;
    const int bi  = kg >> 10;

    const float4* src = (const float4*)(x1 + (size_t)kg * CV + j8 * 8);
    const float4 v0 = src[0], v1 = src[1];
    const float vv[8] = {v0.x, v0.y, v0.z, v0.w, v1.x, v1.y, v1.z, v1.w};
    short8 hi, lo;
    #pragma unroll
    for (int i = 0; i < 8; ++i) {
        const unsigned short h = f2bf(vv[i]);
        hi[i] = (short)h;
        lo[i] = (short)f2bf(vv[i] - bf2f(h));
    }
    char* base = (char*)ximg + ((size_t)(bi * 16 + ch)) * 16384;
    const int off = kk * 128 + ((j8 * 16) ^ ((kk & 7) << 4));
    *(short8*)(base + off) = hi;
    *(short8*)(base + 8192 + off) = lo;
}

// ---------------- Kernel 0b: pos1 -> packed float4 image -------------------
__global__ __launch_bounds__(256) void cvt_pos_kernel(
    const float* __restrict__ pos1, float4* __restrict__ pos1p, int n)
{
    const int k = blockIdx.x * 256 + threadIdx.x;
    if (k < n) {
        float4 v;
        v.x = pos1[k * 3 + 0];
        v.y = pos1[k * 3 + 1];
        v.z = pos1[k * 3 + 2];
        v.w = 0.f;
        pos1p[k] = v;
    }
}

// ---------------- Kernel A: MFMA corr + softmax sums + flow + e(bf16) ------
__global__ __launch_bounds__(256) void corr_probs_kernel(
    const float* __restrict__ x0, const unsigned short* __restrict__ ximg,
    const float* __restrict__ pos0, const float* __restrict__ pos1,
    float* __restrict__ out_flow, unsigned short* __restrict__ probs_bf,
    float* __restrict__ rscale)
{
    const int r0 = blockIdx.x * RT;
    const int b  = r0 >> 11;
    const int t  = threadIdx.x;
    const int lane = t & 63;
    const int w    = t >> 6;
    const int l15  = lane & 15;
    const int q    = lane >> 4;

    __shared__ __align__(16) short sX0h[RT * 64], sX0l[RT * 64];   // 2KB+2KB
    __shared__ __align__(16) char  sX1[2][16384];                  // 32KB dbuf
    __shared__ __align__(16) float sp1[L1V * 3];                   // 12KB
    __shared__ float sred[4][RT][4];

    // stage x0 tile hi/lo bf16 (swizzled), once
    {
        const int row = t >> 4;
        const float4 v = ((const float4*)(x0 + (size_t)(r0 + row) * CV))[t & 15];
        const unsigned short h0 = f2bf(v.x), h1 = f2bf(v.y), h2 = f2bf(v.z), h3 = f2bf(v.w);
        const short4v hi = { (short)h0, (short)h1, (short)h2, (short)h3 };
        const short4v lo = { (short)f2bf(v.x - bf2f(h0)), (short)f2bf(v.y - bf2f(h1)),
                             (short)f2bf(v.z - bf2f(h2)), (short)f2bf(v.w - bf2f(h3)) };
        const int off = row * 128 + (((t & 15) * 8) ^ ((row & 7) << 4));
        *(short4v*)((char*)sX0h + off) = hi;
        *(short4v*)((char*)sX0l + off) = lo;
    }
    // stage all pos1 (1024 x 3 floats), once
    {
        const float4* ps = (const float4*)(pos1 + (size_t)b * L1V * 3);
        #pragma unroll
        for (int i = 0; i < 3; ++i)
            ((float4*)sp1)[i * 256 + t] = ps[i * 256 + t];
    }

    const char* img = (const char*)ximg + (size_t)b * (16 * 16384);
    // prologue: DMA chunk 0 into buf 0
    #pragma unroll
    for (int i = 0; i < 4; ++i)
        gload16(img + (w * 4 + i) * 1024 + lane * 16,
                sX1[0] + (w * 4 + i) * 1024);
    __syncthreads();    // drains prologue DMA + covers sX0/sp1 writes

    const int ma    = w * 16 + l15;
    const int abase = ma * 128;
    const int asw   = (ma & 7) << 4;
    const int bbase = l15 * 128;
    const int bsw   = (l15 & 7) << 4;

    // hoist loop-invariant x0 fragments to registers (n=l15, k=q*8 (+32))
    const int ka0 = (q * 8) * 2, ka1 = (32 + q * 8) * 2;
    const short8 bh0 = *(const short8*)((const char*)sX0h + bbase + (ka0 ^ bsw));
    const short8 bh1 = *(const short8*)((const char*)sX0h + bbase + (ka1 ^ bsw));
    const short8 bl0 = *(const short8*)((const char*)sX0l + bbase + (ka0 ^ bsw));
    const short8 bl1 = *(const short8*)((const char*)sX0l + bbase + (ka1 ^ bsw));

    float s_a = 0.f, cx_a = 0.f, cy_a = 0.f, cz_a = 0.f;

    for (int ch = 0; ch < 16; ++ch) {
        const int buf = ch & 1;
        if (ch < 15) {
            const char* s = img + (ch + 1) * 16384;
            char* d = sX1[buf ^ 1];
            #pragma unroll
            for (int i = 0; i < 4; ++i)
                gload16(s + (w * 4 + i) * 1024 + lane * 16, d + (w * 4 + i) * 1024);
            asm volatile("s_waitcnt vmcnt(4)" ::: "memory");  // ch's DMA done
        } else {
            asm volatile("s_waitcnt vmcnt(1)" ::: "memory");
        }
        __builtin_amdgcn_s_barrier();

        const char* Xh = sX1[buf];
        const char* Xl = Xh + 8192;
        f32x4 acc = {0.f, 0.f, 0.f, 0.f};
        {
            const short8 ah0 = *(const short8*)(Xh + abase + (ka0 ^ asw));
            const short8 al0 = *(const short8*)(Xl + abase + (ka0 ^ asw));
            const short8 ah1 = *(const short8*)(Xh + abase + (ka1 ^ asw));
            const short8 al1 = *(const short8*)(Xl + abase + (ka1 ^ asw));
            acc = __builtin_amdgcn_mfma_f32_16x16x32_bf16(ah0, bh0, acc, 0, 0, 0);
            acc = __builtin_amdgcn_mfma_f32_16x16x32_bf16(ah0, bl0, acc, 0, 0, 0);
            acc = __builtin_amdgcn_mfma_f32_16x16x32_bf16(al0, bh0, acc, 0, 0, 0);
            acc = __builtin_amdgcn_mfma_f32_16x16x32_bf16(ah1, bh1, acc, 0, 0, 0);
            acc = __builtin_amdgcn_mfma_f32_16x16x32_bf16(ah1, bl1, acc, 0, 0, 0);
            acc = __builtin_amdgcn_mfma_f32_16x16x32_bf16(al1, bh1, acc, 0, 0, 0);
        }

        unsigned short eb[4];
        #pragma unroll
        for (int rg = 0; rg < 4; ++rg) {
            const int kc = ch * 64 + w * 16 + q * 4 + rg;
            const float e = __expf(acc[rg] * 0.125f);
            eb[rg] = f2bf(e);
            s_a += e;
            cx_a = fmaf(e, sp1[kc * 3 + 0], cx_a);
            cy_a = fmaf(e, sp1[kc * 3 + 1], cy_a);
            cz_a = fmaf(e, sp1[kc * 3 + 2], cz_a);
        }
        const short4v ev = { (short)eb[0], (short)eb[1], (short)eb[2], (short)eb[3] };
        *(short4v*)(probs_bf + (size_t)(r0 + l15) * L1V + ch * 64 + w * 16 + q * 4) = ev;

        __builtin_amdgcn_s_barrier();
    }

    // reduce the 4 key-quads within the wave, then across waves
    s_a  += __shfl_xor(s_a, 16, 64);  s_a  += __shfl_xor(s_a, 32, 64);
    cx_a += __shfl_xor(cx_a, 16, 64); cx_a += __shfl_xor(cx_a, 32, 64);
    cy_a += __shfl_xor(cy_a, 16, 64); cy_a += __shfl_xor(cy_a, 32, 64);
    cz_a += __shfl_xor(cz_a, 16, 64); cz_a += __shfl_xor(cz_a, 32, 64);
    if (lane < 16) {
        sred[w][l15][0] = s_a;  sred[w][l15][1] = cx_a;
        sred[w][l15][2] = cy_a; sred[w][l15][3] = cz_a;
    }
    __syncthreads();

    if (t < RT) {
        const float S  = (sred[0][t][0] + sred[1][t][0]) + (sred[2][t][0] + sred[3][t][0]);
        const float CX = (sred[0][t][1] + sred[1][t][1]) + (sred[2][t][1] + sred[3][t][1]);
        const float CY = (sred[0][t][2] + sred[1][t][2]) + (sred[2][t][2] + sred[3][t][2]);
        const float CZ = (sred[0][t][3] + sred[1][t][3]) + (sred[2][t][3] + sred[3][t][3]);
        const float rs = 1.0f / S;
        rscale[r0 + t] = rs;
        out_flow[(r0 + t) * 3 + 0] = CX * rs - pos0[(r0 + t) * 3 + 0];
        out_flow[(r0 + t) * 3 + 1] = CY * rs - pos0[(r0 + t) * 3 + 1];
        out_flow[(r0 + t) * 3 + 2] = CZ * rs - pos0[(r0 + t) * 3 + 2];
    }
}

// ---------------- Kernel B: one-wave-per-row MFMA splat, barrier-free ------
__global__ __launch_bounds__(256, 4) void splat_mfma_kernel(
    const unsigned short* __restrict__ probs_bf, const float* __restrict__ rscale,
    const float* __restrict__ pos0, const float4* __restrict__ pos1p,
    float* __restrict__ out_grid)
{
    const int t    = threadIdx.x;
    const int lane = t & 63;
    const int w    = t >> 6;
    const int r    = blockIdx.x * 4 + w;     // one row per wave
    const int b    = r >> 11;

    __shared__ __align__(16) short sAll[4][4608];   // per wave: sR 4096 + sZ 512
    char* sR = (char*)sAll[w];
    char* sZ = (char*)sAll[w] + 8192;

    const float inv = 1.0f / 0.12f;
    const float p0x = pos0[r * 3 + 0];
    const float p0y = pos0[r * 3 + 1];
    const float p0z = pos0[r * 3 + 2];
    const float4* p1p = pos1p + (size_t)b * L1V;
    const unsigned short* prow = probs_bf + (size_t)r * L1V;

    // window base from pos0 only (monotone lower bound; 8-wide window covers)
    const int mnx = (int)floorf((-0.3f - p0x + 0.72f) * inv - 0.5f);
    const int mny = (int)floorf((-0.3f - p0y + 0.72f) * inv - 0.5f);
    const int mnz = (int)floorf((-0.3f - p0z + 0.72f) * inv - 0.5f);

    // zero this wave's slab: 9216B = 9 x b128 per lane
    {
        const short8 z8 = {0, 0, 0, 0, 0, 0, 0, 0};
        #pragma unroll
        for (int j = 0; j < 9; ++j)
            *(short8*)(sR + lane * 16 + j * 1024) = z8;
    }

    const int l15  = lane & 15;
    const int q16  = (lane >> 4) * 16;
    const int asw  = (l15 & 7) << 4;
    const int aoff0 = l15 * 128 + ((0  + q16) ^ asw);
    const int aoff1 = l15 * 128 + ((64 + q16) ^ asw);
    const int zrow = l15 & 7;
    const int bsw  = zrow << 4;
    const int boff0 = zrow * 128 + ((0  + q16) ^ bsw);
    const int boff1 = zrow * 128 + ((64 + q16) ^ bsw);
    const int lane2 = lane * 2;

    f32x4 acc[4];
    #pragma unroll
    for (int mt = 0; mt < 4; ++mt) acc[mt] = (f32x4){0.f, 0.f, 0.f, 0.f};

    char *P0 = sR + lane2, *P1 = sR + lane2, *P2 = sR + lane2,
         *P3 = sR + lane2, *P4 = sZ + lane2, *P5 = sZ + lane2;

    float4 pc = p1p[lane];
    float pv  = bf2f(prow[lane]);

    asm volatile("s_waitcnt lgkmcnt(0)" ::: "memory");   // slab zeroed (once)

    for (int ch = 0; ch < 16; ++ch) {
        float4 nc = pc;
        float  nv = pv;
        if (ch < 15) {
            const int nk = (ch + 1) * 64 + lane;
            nc = p1p[nk];
            nv = bf2f(prow[nk]);
        }

        const float ax = ((pc.x - p0x) + 0.72f) * inv - 0.5f;
        const float ay = ((pc.y - p0y) + 0.72f) * inv - 0.5f;
        const float az = ((pc.z - p0z) + 0.72f) * inv - 0.5f;
        const float fxf = floorf(ax), fyf = floorf(ay), fzf = floorf(az);
        const float fx = ax - fxf, fy = ay - fyf, fz = az - fzf;
        const int rix = (int)fxf - mnx;          // 0..6
        const int riy = (int)fyf - mny;
        const int riz = (int)fzf - mnz;
        const float wx0 = 1.f - fx, wy0 = 1.f - fy, wz0 = 1.f - fz;
        const float a0p = pv * wx0, a1p = pv * fx;
        const unsigned short r00 = f2bf(a0p * wy0), r01 = f2bf(a0p * fy);
        const unsigned short r10 = f2bf(a1p * wy0), r11 = f2bf(a1p * fy);
        const unsigned short z0 = f2bf(wz0), z1 = f2bf(fz);

        const int c00 = rix * 8 + riy;
        char* A0 = sR + (c00    ) * 128 + (lane2 ^ (((c00    ) & 7) << 4));
        char* A1 = sR + (c00 + 1) * 128 + (lane2 ^ (((c00 + 1) & 7) << 4));
        char* A2 = sR + (c00 + 8) * 128 + (lane2 ^ (((c00 + 8) & 7) << 4));
        char* A3 = sR + (c00 + 9) * 128 + (lane2 ^ (((c00 + 9) & 7) << 4));
        char* Z0a = sZ + riz * 128 + (lane2 ^ (riz << 4));
        char* Z1a = sZ + (riz + 1) * 128 + (lane2 ^ ((riz + 1) << 4));

        // rezero previous chunk's slots, then stage current (in-order DS pipe)
        *(short*)P0 = 0; *(short*)P1 = 0; *(short*)P2 = 0;
        *(short*)P3 = 0; *(short*)P4 = 0; *(short*)P5 = 0;
        *(short*)A0 = (short)r00; *(short*)A1 = (short)r01;
        *(short*)A2 = (short)r10; *(short*)A3 = (short)r11;
        *(short*)Z0a = (short)z0; *(short*)Z1a = (short)z1;

        const short8 b0 = *(const short8*)(sZ + boff0);
        const short8 b1 = *(const short8*)(sZ + boff1);
        #pragma unroll
        for (int mt = 0; mt < 4; ++mt) {
            const short8 a0 = *(const short8*)(sR + mt * 2048 + aoff0);
            const short8 a1 = *(const short8*)(sR + mt * 2048 + aoff1);
            acc[mt] = __builtin_amdgcn_mfma_f32_16x16x32_bf16(a0, b0, acc[mt], 0, 0, 0);
            acc[mt] = __builtin_amdgcn_mfma_f32_16x16x32_bf16(a1, b1, acc[mt], 0, 0, 0);
        }

        P0 = A0; P1 = A1; P2 = A2; P3 = A3; P4 = Z0a; P5 = Z1a;
        pc = nc; pv = nv;
    }

    // ---- writeout: coalesced zero-fill, then masked scatter from acc ----
    const float rs = rscale[r];
    float* og = out_grid + (size_t)r * G3;
    {
        const float4 z4 = {0.f, 0.f, 0.f, 0.f};
        float4* og4 = (float4*)og;
        #pragma unroll
        for (int j = 0; j < 6; ++j) og4[j * 64 + lane] = z4;   // 1536 floats
        if (lane < 48) og4[384 + lane] = z4;                   // remaining 192
    }
    asm volatile("s_waitcnt vmcnt(0)" ::: "memory");

    const int zB = lane & 15;
    if (zB < 8) {
        const int gz = mnz + zB;
        if (gz <= 11) {
            const int h4 = (lane >> 4) * 4;
            const int rxm = 11 - mnx;
            const int rym = 11 - mny;
            float* base2 = og + mnx * 144 + mny * 12 + gz;
            #pragma unroll
            for (int mt = 0; mt < 4; ++mt) {
                #pragma unroll
                for (int rg = 0; rg < 4; ++rg) {
                    const int c  = mt * 16 + h4 + rg;
                    const int rx = c >> 3;
                    const int ry = c & 7;
                    if (rx <= rxm && ry <= rym)
                        base2[rx * 144 + ry * 12] = acc[mt][rg] * rs;
                }
            }
        }
    }
}

extern "C" void kernel_launch(void* const* d_in, const int* in_sizes, int n_in,
                              void* d_out, int out_size, void* d_ws, size_t ws_size,
                              hipStream_t stream) {
    const float* x0   = (const float*)d_in[0];
    const float* x1   = (const float*)d_in[1];
    const float* pos0 = (const float*)d_in[2];
    const float* pos1 = (const float*)d_in[3];
    float* out = (float*)d_out;

    const int B    = in_sizes[0] / (L0V * CV);   // 4
    const int rows = B * L0V;                    // 8192

    float* out_flow = out;
    float* out_grid = out + (size_t)rows * 3;

    // ws layout: probs_bf (16.78MB) | rscale (32KB) | ximg (1MB) | pos1p (64KB)
    unsigned short* probs_bf = (unsigned short*)d_ws;
    float* rscale = (float*)((char*)d_ws + (size_t)rows * L1V * sizeof(unsigned short));
    unsigned short* ximg = (unsigned short*)((char*)rscale + (size_t)rows * sizeof(float));
    float4* pos1p = (float4*)((char*)ximg + (size_t)B * 16 * 16384);

    const int nkeys = B * L1V;
    cvt_x1_kernel<<<(B * L1V * CV / 8) / 256, 256, 0, stream>>>(x1, ximg);
    cvt_pos_kernel<<<(nkeys + 255) / 256, 256, 0, stream>>>(pos1, pos1p, nkeys);
    corr_probs_kernel<<<rows / RT, 256, 0, stream>>>(
        x0, ximg, pos0, pos1, out_flow, probs_bf, rscale);
    splat_mfma_kernel<<<rows / 4, 256, 0, stream>>>(
        probs_bf, rscale, pos0, pos1p, out_grid);
}

// Round 14
// 60.044 us; speedup vs baseline: 1.0384x; 1.0384x over previous
//
#include <hip/hip_runtime.h>
#include <stdint.h>

// CoarseMatching R14 (= R13 with the addrspacecast compile fix):
//  - cvt kernel: x1 -> pre-swizzled hi/lo bf16 chunk images + packed pos1p.
//  - fused kernel, 16 rows/block, 68KB LDS (2 blocks/CU):
//    A-phase: dbuf global_load_lds staging, 6 MFMA/chunk (hi/lo bf16 corr),
//      exp -> e stored bf16 to LDS sE tile (col ^= row<<2 swizzle).
//      Last chunk waits vmcnt(0) (fixes R11/12 latent race).
//    B-phase: per wave, 4 rows sequential; barrier-free MFMA splat from
//      private slab (overlaid on A's staging LDS); flow/centroid/denom
//      accumulated here; grid scaled by 1/S at writeout.
//  Fix vs R13: no pointer-array initializer from LDS (addrspacecast issue);
//  buffer pointers computed arithmetically per iteration.
#define GRID_NUM 12
#define G3 1728
#define L0V 2048
#define L1V 1024
#define CV 64
#define RT 16               // query rows per block

typedef __attribute__((ext_vector_type(8))) short short8;
typedef __attribute__((ext_vector_type(4))) short short4v;
typedef __attribute__((ext_vector_type(4))) float f32x4;

__device__ __forceinline__ unsigned short f2bf(float f) {
    union { float f; unsigned u; } v; v.f = f;
    unsigned u = v.u;
    u += 0x7fffu + ((u >> 16) & 1u);     // round-to-nearest-even
    return (unsigned short)(u >> 16);
}
__device__ __forceinline__ float bf2f(unsigned short h) {
    union { unsigned u; float f; } v; v.u = ((unsigned)h) << 16;
    return v.f;
}

__device__ __forceinline__ void gload16(const void* g, void* l) {
    __builtin_amdgcn_global_load_lds(
        (const __attribute__((address_space(1))) unsigned int*)(uintptr_t)g,
        (__attribute__((address_space(3))) unsigned int*)(uintptr_t)l,
        16, 0, 0);
}

// ---------- Kernel 0: x1 -> swizzled hi/lo bf16 images, pos1 -> float4 -----
__global__ __launch_bounds__(256) void cvt_kernel(
    const float* __restrict__ x1, const float* __restrict__ pos1,
    unsigned short* __restrict__ ximg, float4* __restrict__ pos1p, int nkeys)
{
    const int g  = blockIdx.x * 256 + threadIdx.x;   // 32768 total
    const int kg = g >> 3;                           // global key (b*1024+key)
    const int j8 = g & 7;
    const int key = kg & 1023;
    const int ch  = key >> 6;
    const int kk  = key & 63;
    const int bi  = kg >> 10;

    const float4* src = (const float4*)(x1 + (size_t)kg * CV + j8 * 8);
    const float4 v0 = src[0], v1 = src[1];
    const float vv[8] = {v0.x, v0.y, v0.z, v0.w, v1.x, v1.y, v1.z, v1.w};
    short8 hi, lo;
    #pragma unroll
    for (int i = 0; i < 8; ++i) {
        const unsigned short h = f2bf(vv[i]);
        hi[i] = (short)h;
        lo[i] = (short)f2bf(vv[i] - bf2f(h));
    }
    char* base = (char*)ximg + ((size_t)(bi * 16 + ch)) * 16384;
    const int off = kk * 128 + ((j8 * 16) ^ ((kk & 7) << 4));
    *(short8*)(base + off) = hi;
    *(short8*)(base + 8192 + off) = lo;

    if (g < nkeys) {
        float4 v;
        v.x = pos1[g * 3 + 0];
        v.y = pos1[g * 3 + 1];
        v.z = pos1[g * 3 + 2];
        v.w = 0.f;
        pos1p[g] = v;
    }
}

// ---------------- Fused kernel: corr+softmax (A) then splat (B) ------------
__global__ __launch_bounds__(256) void fused_kernel(
    const float* __restrict__ x0, const unsigned short* __restrict__ ximg,
    const float* __restrict__ pos0, const float4* __restrict__ pos1p,
    float* __restrict__ out_flow, float* __restrict__ out_grid)
{
    const int r0 = blockIdx.x * RT;
    const int b  = r0 >> 11;
    const int t  = threadIdx.x;
    const int lane = t & 63;
    const int w    = t >> 6;
    const int l15  = lane & 15;
    const int q    = lane >> 4;

    // pool layout A: [sX0h 2K][sX0l 2K][sX1 dbuf 2x16K][sE 32K] = 68KB
    //             B: [slabs 4x9216 = 36K               ][sE 32K]
    __shared__ __align__(16) char pool[69632];
    char* sX0h = pool;
    char* sX0l = pool + 2048;
    char* sE   = pool + 36864;

    // ---------------- A phase ----------------
    {
        const int row = t >> 4;
        const float4 v = ((const float4*)(x0 + (size_t)(r0 + row) * CV))[t & 15];
        const unsigned short h0 = f2bf(v.x), h1 = f2bf(v.y), h2 = f2bf(v.z), h3 = f2bf(v.w);
        const short4v hi = { (short)h0, (short)h1, (short)h2, (short)h3 };
        const short4v lo = { (short)f2bf(v.x - bf2f(h0)), (short)f2bf(v.y - bf2f(h1)),
                             (short)f2bf(v.z - bf2f(h2)), (short)f2bf(v.w - bf2f(h3)) };
        const int off = row * 128 + (((t & 15) * 8) ^ ((row & 7) << 4));
        *(short4v*)(sX0h + off) = hi;
        *(short4v*)(sX0l + off) = lo;
    }

    const char* img = (const char*)ximg + (size_t)b * (16 * 16384);
    #pragma unroll
    for (int i = 0; i < 4; ++i)
        gload16(img + (w * 4 + i) * 1024 + lane * 16,
                pool + 4096 + (w * 4 + i) * 1024);
    __syncthreads();    // drains prologue DMA + covers sX0 writes

    const int ma    = w * 16 + l15;
    const int abase = ma * 128;
    const int asw   = (ma & 7) << 4;
    const int bbase = l15 * 128;
    const int bsw   = (l15 & 7) << 4;
    const int ka0 = (q * 8) * 2, ka1 = (32 + q * 8) * 2;
    // loop-invariant x0 fragments (read before slab overlay destroys sX0)
    const short8 bh0 = *(const short8*)(sX0h + bbase + (ka0 ^ bsw));
    const short8 bh1 = *(const short8*)(sX0h + bbase + (ka1 ^ bsw));
    const short8 bl0 = *(const short8*)(sX0l + bbase + (ka0 ^ bsw));
    const short8 bl1 = *(const short8*)(sX0l + bbase + (ka1 ^ bsw));

    for (int ch = 0; ch < 16; ++ch) {
        const int buf = ch & 1;
        if (ch < 15) {
            const char* s = img + (ch + 1) * 16384;
            char* d = pool + 4096 + (buf ^ 1) * 16384;
            #pragma unroll
            for (int i = 0; i < 4; ++i)
                gload16(s + (w * 4 + i) * 1024 + lane * 16, d + (w * 4 + i) * 1024);
            asm volatile("s_waitcnt vmcnt(4)" ::: "memory");
        } else {
            asm volatile("s_waitcnt vmcnt(0)" ::: "memory");
        }
        __builtin_amdgcn_s_barrier();

        const char* Xh = pool + 4096 + buf * 16384;
        const char* Xl = Xh + 8192;
        f32x4 acc = {0.f, 0.f, 0.f, 0.f};
        {
            const short8 ah0 = *(const short8*)(Xh + abase + (ka0 ^ asw));
            const short8 al0 = *(const short8*)(Xl + abase + (ka0 ^ asw));
            const short8 ah1 = *(const short8*)(Xh + abase + (ka1 ^ asw));
            const short8 al1 = *(const short8*)(Xl + abase + (ka1 ^ asw));
            acc = __builtin_amdgcn_mfma_f32_16x16x32_bf16(ah0, bh0, acc, 0, 0, 0);
            acc = __builtin_amdgcn_mfma_f32_16x16x32_bf16(ah0, bl0, acc, 0, 0, 0);
            acc = __builtin_amdgcn_mfma_f32_16x16x32_bf16(al0, bh0, acc, 0, 0, 0);
            acc = __builtin_amdgcn_mfma_f32_16x16x32_bf16(ah1, bh1, acc, 0, 0, 0);
            acc = __builtin_amdgcn_mfma_f32_16x16x32_bf16(ah1, bl1, acc, 0, 0, 0);
            acc = __builtin_amdgcn_mfma_f32_16x16x32_bf16(al1, bh1, acc, 0, 0, 0);
        }

        unsigned short eb[4];
        #pragma unroll
        for (int rg = 0; rg < 4; ++rg)
            eb[rg] = f2bf(__expf(acc[rg] * 0.125f));
        const short4v ev = { (short)eb[0], (short)eb[1], (short)eb[2], (short)eb[3] };
        // e[row=l15][key] with key-col swizzled by row: col ^= l15<<2
        const int col = (ch * 64 + w * 16 + q * 4) ^ (l15 << 2);
        *(short4v*)(sE + l15 * 2048 + col * 2) = ev;

        __builtin_amdgcn_s_barrier();
    }
    __syncthreads();   // all sE written; staging LDS free for slabs

    // ---------------- B phase: per-wave splat of 4 rows ----------------
    char* sR = pool + w * 9216;
    char* sZ = sR + 8192;
    const float inv = 1.0f / 0.12f;
    const float4* p1p = pos1p + (size_t)b * L1V;

    // zero this wave's slab once (9216B = 9 x b128 per lane)
    {
        const short8 z8 = {0, 0, 0, 0, 0, 0, 0, 0};
        #pragma unroll
        for (int j = 0; j < 9; ++j)
            *(short8*)(sR + lane * 16 + j * 1024) = z8;
    }

    const int q16  = (lane >> 4) * 16;
    const int asw2 = (l15 & 7) << 4;
    const int aoff0 = l15 * 128 + ((0  + q16) ^ asw2);
    const int aoff1 = l15 * 128 + ((64 + q16) ^ asw2);
    const int zrow = l15 & 7;
    const int bsw2 = zrow << 4;
    const int boff0 = zrow * 128 + ((0  + q16) ^ bsw2);
    const int boff1 = zrow * 128 + ((64 + q16) ^ bsw2);
    const int lane2 = lane * 2;

    for (int rr4 = 0; rr4 < 4; ++rr4) {
        const int rrow = w * 4 + rr4;        // row within tile (= sE row)
        const int r    = r0 + rrow;
        const float p0x = pos0[r * 3 + 0];
        const float p0y = pos0[r * 3 + 1];
        const float p0z = pos0[r * 3 + 2];
        const int mnx = (int)floorf((-0.3f - p0x + 0.72f) * inv - 0.5f);
        const int mny = (int)floorf((-0.3f - p0y + 0.72f) * inv - 0.5f);
        const int mnz = (int)floorf((-0.3f - p0z + 0.72f) * inv - 0.5f);
        const int esw = rrow << 2;

        f32x4 acc[4];
        #pragma unroll
        for (int mt = 0; mt < 4; ++mt) acc[mt] = (f32x4){0.f, 0.f, 0.f, 0.f};
        float s_a = 0.f, cx_a = 0.f, cy_a = 0.f, cz_a = 0.f;

        char *P0 = sR + lane2, *P1 = sR + lane2, *P2 = sR + lane2,
             *P3 = sR + lane2, *P4 = sZ + lane2, *P5 = sZ + lane2;

        float4 pc = p1p[lane];
        float  pv = bf2f(*(const unsigned short*)(sE + rrow * 2048 + (lane ^ esw) * 2));

        for (int ch = 0; ch < 16; ++ch) {
            float4 nc = pc;
            float  nv = pv;
            if (ch < 15) {
                const int nk = (ch + 1) * 64 + lane;
                nc = p1p[nk];
                nv = bf2f(*(const unsigned short*)(sE + rrow * 2048 + (nk ^ esw) * 2));
            }

            // flow/denom accumulation (f32 e)
            s_a += pv;
            cx_a = fmaf(pv, pc.x, cx_a);
            cy_a = fmaf(pv, pc.y, cy_a);
            cz_a = fmaf(pv, pc.z, cz_a);

            const float ax = ((pc.x - p0x) + 0.72f) * inv - 0.5f;
            const float ay = ((pc.y - p0y) + 0.72f) * inv - 0.5f;
            const float az = ((pc.z - p0z) + 0.72f) * inv - 0.5f;
            const float fxf = floorf(ax), fyf = floorf(ay), fzf = floorf(az);
            const float fx = ax - fxf, fy = ay - fyf, fz = az - fzf;
            const int rix = (int)fxf - mnx;          // 0..6
            const int riy = (int)fyf - mny;
            const int riz = (int)fzf - mnz;
            const float wx0 = 1.f - fx, wy0 = 1.f - fy, wz0 = 1.f - fz;
            const float a0p = pv * wx0, a1p = pv * fx;
            const unsigned short r00 = f2bf(a0p * wy0), r01 = f2bf(a0p * fy);
            const unsigned short r10 = f2bf(a1p * wy0), r11 = f2bf(a1p * fy);
            const unsigned short z0 = f2bf(wz0), z1 = f2bf(fz);

            const int c00 = rix * 8 + riy;
            char* A0 = sR + (c00    ) * 128 + (lane2 ^ (((c00    ) & 7) << 4));
            char* A1 = sR + (c00 + 1) * 128 + (lane2 ^ (((c00 + 1) & 7) << 4));
            char* A2 = sR + (c00 + 8) * 128 + (lane2 ^ (((c00 + 8) & 7) << 4));
            char* A3 = sR + (c00 + 9) * 128 + (lane2 ^ (((c00 + 9) & 7) << 4));
            char* Z0a = sZ + riz * 128 + (lane2 ^ (riz << 4));
            char* Z1a = sZ + (riz + 1) * 128 + (lane2 ^ ((riz + 1) << 4));

            // rezero previous chunk's slots, then stage (in-order DS pipe)
            *(short*)P0 = 0; *(short*)P1 = 0; *(short*)P2 = 0;
            *(short*)P3 = 0; *(short*)P4 = 0; *(short*)P5 = 0;
            *(short*)A0 = (short)r00; *(short*)A1 = (short)r01;
            *(short*)A2 = (short)r10; *(short*)A3 = (short)r11;
            *(short*)Z0a = (short)z0; *(short*)Z1a = (short)z1;

            const short8 b0 = *(const short8*)(sZ + boff0);
            const short8 b1 = *(const short8*)(sZ + boff1);
            #pragma unroll
            for (int mt = 0; mt < 4; ++mt) {
                const short8 a0 = *(const short8*)(sR + mt * 2048 + aoff0);
                const short8 a1 = *(const short8*)(sR + mt * 2048 + aoff1);
                acc[mt] = __builtin_amdgcn_mfma_f32_16x16x32_bf16(a0, b0, acc[mt], 0, 0, 0);
                acc[mt] = __builtin_amdgcn_mfma_f32_16x16x32_bf16(a1, b1, acc[mt], 0, 0, 0);
            }

            P0 = A0; P1 = A1; P2 = A2; P3 = A3; P4 = Z0a; P5 = Z1a;
            pc = nc; pv = nv;
        }

        // clear last chunk's slots so slab is all-zero for the next row
        *(short*)P0 = 0; *(short*)P1 = 0; *(short*)P2 = 0;
        *(short*)P3 = 0; *(short*)P4 = 0; *(short*)P5 = 0;

        // wave-reduce denom + centroid
        #pragma unroll
        for (int o = 1; o < 64; o <<= 1) {
            s_a  += __shfl_xor(s_a, o, 64);
            cx_a += __shfl_xor(cx_a, o, 64);
            cy_a += __shfl_xor(cy_a, o, 64);
            cz_a += __shfl_xor(cz_a, o, 64);
        }
        const float rs = 1.0f / s_a;
        if (lane == 0) {
            out_flow[r * 3 + 0] = cx_a * rs - p0x;
            out_flow[r * 3 + 1] = cy_a * rs - p0y;
            out_flow[r * 3 + 2] = cz_a * rs - p0z;
        }

        // writeout: coalesced zero-fill, then masked scatter from acc
        float* og = out_grid + (size_t)r * G3;
        {
            const float4 z4 = {0.f, 0.f, 0.f, 0.f};
            float4* og4 = (float4*)og;
            #pragma unroll
            for (int j = 0; j < 6; ++j) og4[j * 64 + lane] = z4;
            if (lane < 48) og4[384 + lane] = z4;
        }
        asm volatile("s_waitcnt vmcnt(0)" ::: "memory");

        const int zB = lane & 15;
        if (zB < 8) {
            const int gz = mnz + zB;
            if (gz <= 11) {
                const int h4 = (lane >> 4) * 4;
                const int rxm = 11 - mnx;
                const int rym = 11 - mny;
                float* base2 = og + mnx * 144 + mny * 12 + gz;
                #pragma unroll
                for (int mt = 0; mt < 4; ++mt) {
                    #pragma unroll
                    for (int rg = 0; rg < 4; ++rg) {
                        const int c  = mt * 16 + h4 + rg;
                        const int rx = c >> 3;
                        const int ry = c & 7;
                        if (rx <= rxm && ry <= rym)
                            base2[rx * 144 + ry * 12] = acc[mt][rg] * rs;
                    }
                }
            }
        }
    }
}

extern "C" void kernel_launch(void* const* d_in, const int* in_sizes, int n_in,
                              void* d_out, int out_size, void* d_ws, size_t ws_size,
                              hipStream_t stream) {
    const float* x0   = (const float*)d_in[0];
    const float* x1   = (const float*)d_in[1];
    const float* pos0 = (const float*)d_in[2];
    const float* pos1 = (const float*)d_in[3];
    float* out = (float*)d_out;

    const int B    = in_sizes[0] / (L0V * CV);   // 4
    const int rows = B * L0V;                    // 8192

    float* out_flow = out;
    float* out_grid = out + (size_t)rows * 3;

    // ws layout: ximg (1MB) | pos1p (64KB)
    unsigned short* ximg = (unsigned short*)d_ws;
    float4* pos1p = (float4*)((char*)d_ws + (size_t)B * 16 * 16384);

    const int nkeys = B * L1V;
    cvt_kernel<<<(B * L1V * CV / 8) / 256, 256, 0, stream>>>(
        x1, pos1, ximg, pos1p, nkeys);
    fused_kernel<<<rows / RT, 256, 0, stream>>>(
        x0, ximg, pos0, pos1p, out_flow, out_grid);
}

// Round 15
// 57.904 us; speedup vs baseline: 1.0768x; 1.0370x over previous
//
#include <hip/hip_runtime.h>
#include <stdint.h>

// CoarseMatching R15: back to split (R11 structure), three cuts:
//  - x1 staged single-plane bf16 (x0 keeps hi/lo): 4 MFMA/chunk, half DMA.
//  - A barrier-free: each wave's DMA region == its read region; per-wave
//    vmcnt + sched_barrier(0) ordering only.
//  - B: per-row k-constants -> per-key grid coord is one fma.
#define GRID_NUM 12
#define G3 1728
#define L0V 2048
#define L1V 1024
#define CV 64
#define RT 16               // query rows per block (kernel A)

typedef __attribute__((ext_vector_type(8))) short short8;
typedef __attribute__((ext_vector_type(4))) short short4v;
typedef __attribute__((ext_vector_type(4))) float f32x4;

__device__ __forceinline__ unsigned short f2bf(float f) {
    union { float f; unsigned u; } v; v.f = f;
    unsigned u = v.u;
    u += 0x7fffu + ((u >> 16) & 1u);     // round-to-nearest-even
    return (unsigned short)(u >> 16);
}
__device__ __forceinline__ float bf2f(unsigned short h) {
    union { unsigned u; float f; } v; v.u = ((unsigned)h) << 16;
    return v.f;
}

__device__ __forceinline__ void gload16(const void* g, void* l) {
    __builtin_amdgcn_global_load_lds(
        (const __attribute__((address_space(1))) unsigned int*)(uintptr_t)g,
        (__attribute__((address_space(3))) unsigned int*)(uintptr_t)l,
        16, 0, 0);
}

// ---------- Kernel 0: x1 -> swizzled bf16 images (single plane) + pos1p ----
__global__ __launch_bounds__(256) void cvt_kernel(
    const float* __restrict__ x1, const float* __restrict__ pos1,
    unsigned short* __restrict__ ximg, float4* __restrict__ pos1p, int nkeys)
{
    const int g  = blockIdx.x * 256 + threadIdx.x;   // 32768 total
    const int kg = g >> 3;                           // global key (b*1024+key)
    const int j8 = g & 7;
    const int key = kg & 1023;
    const int ch  = key >> 6;
    const int kk  = key & 63;
    const int bi  = kg >> 10;

    const float4* src = (const float4*)(x1 + (size_t)kg * CV + j8 * 8);
    const float4 v0 = src[0], v1 = src[1];
    short8 hi;
    hi[0] = (short)f2bf(v0.x); hi[1] = (short)f2bf(v0.y);
    hi[2] = (short)f2bf(v0.z); hi[3] = (short)f2bf(v0.w);
    hi[4] = (short)f2bf(v1.x); hi[5] = (short)f2bf(v1.y);
    hi[6] = (short)f2bf(v1.z); hi[7] = (short)f2bf(v1.w);
    char* base = (char*)ximg + ((size_t)(bi * 16 + ch)) * 8192;
    const int off = kk * 128 + ((j8 * 16) ^ ((kk & 7) << 4));
    *(short8*)(base + off) = hi;

    if (g < nkeys) {
        float4 v;
        v.x = pos1[g * 3 + 0];
        v.y = pos1[g * 3 + 1];
        v.z = pos1[g * 3 + 2];
        v.w = 0.f;
        pos1p[g] = v;
    }
}

// ---------------- Kernel A: MFMA corr + softmax sums + flow + e(bf16) ------
__global__ __launch_bounds__(256) void corr_probs_kernel(
    const float* __restrict__ x0, const unsigned short* __restrict__ ximg,
    const float* __restrict__ pos0, const float* __restrict__ pos1,
    float* __restrict__ out_flow, unsigned short* __restrict__ probs_bf,
    float* __restrict__ rscale)
{
    const int r0 = blockIdx.x * RT;
    const int b  = r0 >> 11;
    const int t  = threadIdx.x;
    const int lane = t & 63;
    const int w    = t >> 6;
    const int l15  = lane & 15;
    const int q    = lane >> 4;

    __shared__ __align__(16) short sX0h[RT * 64], sX0l[RT * 64];   // 2KB+2KB
    __shared__ __align__(16) char  sX1[2][8192];                   // 16KB dbuf
    __shared__ __align__(16) float sp1[L1V * 3];                   // 12KB
    __shared__ float sred[4][RT][4];

    // stage x0 tile hi/lo bf16 (swizzled), once
    {
        const int row = t >> 4;
        const float4 v = ((const float4*)(x0 + (size_t)(r0 + row) * CV))[t & 15];
        const unsigned short h0 = f2bf(v.x), h1 = f2bf(v.y), h2 = f2bf(v.z), h3 = f2bf(v.w);
        const short4v hi = { (short)h0, (short)h1, (short)h2, (short)h3 };
        const short4v lo = { (short)f2bf(v.x - bf2f(h0)), (short)f2bf(v.y - bf2f(h1)),
                             (short)f2bf(v.z - bf2f(h2)), (short)f2bf(v.w - bf2f(h3)) };
        const int off = row * 128 + (((t & 15) * 8) ^ ((row & 7) << 4));
        *(short4v*)((char*)sX0h + off) = hi;
        *(short4v*)((char*)sX0l + off) = lo;
    }
    // stage all pos1 (1024 x 3 floats), once
    {
        const float4* ps = (const float4*)(pos1 + (size_t)b * L1V * 3);
        #pragma unroll
        for (int i = 0; i < 3; ++i)
            ((float4*)sp1)[i * 256 + t] = ps[i * 256 + t];
    }

    const char* img = (const char*)ximg + (size_t)b * (16 * 8192);
    // prologue: DMA chunk 0 into buf 0 (own-wave region only)
    #pragma unroll
    for (int i = 0; i < 2; ++i)
        gload16(img + (w * 2 + i) * 1024 + lane * 16,
                sX1[0] + (w * 2 + i) * 1024);
    __syncthreads();    // drains prologue DMA + covers sX0/sp1 writes

    const int ma    = w * 16 + l15;
    const int abase = ma * 128;
    const int asw   = (ma & 7) << 4;
    const int bbase = l15 * 128;
    const int bsw   = (l15 & 7) << 4;
    const int ka0 = (q * 8) * 2, ka1 = (32 + q * 8) * 2;
    // loop-invariant x0 fragments
    const short8 bh0 = *(const short8*)((const char*)sX0h + bbase + (ka0 ^ bsw));
    const short8 bh1 = *(const short8*)((const char*)sX0h + bbase + (ka1 ^ bsw));
    const short8 bl0 = *(const short8*)((const char*)sX0l + bbase + (ka0 ^ bsw));
    const short8 bl1 = *(const short8*)((const char*)sX0l + bbase + (ka1 ^ bsw));

    float s_a = 0.f, cx_a = 0.f, cy_a = 0.f, cz_a = 0.f;

    for (int ch = 0; ch < 16; ++ch) {
        const int buf = ch & 1;
        __builtin_amdgcn_sched_barrier(0);   // pin DMA issue after prior MFMAs
        if (ch < 15) {
            const char* s = img + (ch + 1) * 8192;
            char* d = sX1[buf ^ 1];
            #pragma unroll
            for (int i = 0; i < 2; ++i)
                gload16(s + (w * 2 + i) * 1024 + lane * 16, d + (w * 2 + i) * 1024);
            asm volatile("s_waitcnt vmcnt(2)" ::: "memory");  // ch's DMA done
        } else {
            asm volatile("s_waitcnt vmcnt(0)" ::: "memory");
        }
        __builtin_amdgcn_sched_barrier(0);

        const char* Xh = sX1[buf];
        f32x4 acc = {0.f, 0.f, 0.f, 0.f};
        {
            const short8 ah0 = *(const short8*)(Xh + abase + (ka0 ^ asw));
            const short8 ah1 = *(const short8*)(Xh + abase + (ka1 ^ asw));
            acc = __builtin_amdgcn_mfma_f32_16x16x32_bf16(ah0, bh0, acc, 0, 0, 0);
            acc = __builtin_amdgcn_mfma_f32_16x16x32_bf16(ah0, bl0, acc, 0, 0, 0);
            acc = __builtin_amdgcn_mfma_f32_16x16x32_bf16(ah1, bh1, acc, 0, 0, 0);
            acc = __builtin_amdgcn_mfma_f32_16x16x32_bf16(ah1, bl1, acc, 0, 0, 0);
        }

        unsigned short eb[4];
        #pragma unroll
        for (int rg = 0; rg < 4; ++rg) {
            const int kc = ch * 64 + w * 16 + q * 4 + rg;
            const float e = __expf(acc[rg] * 0.125f);
            eb[rg] = f2bf(e);
            s_a += e;
            cx_a = fmaf(e, sp1[kc * 3 + 0], cx_a);
            cy_a = fmaf(e, sp1[kc * 3 + 1], cy_a);
            cz_a = fmaf(e, sp1[kc * 3 + 2], cz_a);
        }
        const short4v ev = { (short)eb[0], (short)eb[1], (short)eb[2], (short)eb[3] };
        *(short4v*)(probs_bf + (size_t)(r0 + l15) * L1V + ch * 64 + w * 16 + q * 4) = ev;
    }

    // reduce the 4 key-quads within the wave, then across waves
    s_a  += __shfl_xor(s_a, 16, 64);  s_a  += __shfl_xor(s_a, 32, 64);
    cx_a += __shfl_xor(cx_a, 16, 64); cx_a += __shfl_xor(cx_a, 32, 64);
    cy_a += __shfl_xor(cy_a, 16, 64); cy_a += __shfl_xor(cy_a, 32, 64);
    cz_a += __shfl_xor(cz_a, 16, 64); cz_a += __shfl_xor(cz_a, 32, 64);
    if (lane < 16) {
        sred[w][l15][0] = s_a;  sred[w][l15][1] = cx_a;
        sred[w][l15][2] = cy_a; sred[w][l15][3] = cz_a;
    }
    __syncthreads();

    if (t < RT) {
        const float S  = (sred[0][t][0] + sred[1][t][0]) + (sred[2][t][0] + sred[3][t][0]);
        const float CX = (sred[0][t][1] + sred[1][t][1]) + (sred[2][t][1] + sred[3][t][1]);
        const float CY = (sred[0][t][2] + sred[1][t][2]) + (sred[2][t][2] + sred[3][t][2]);
        const float CZ = (sred[0][t][3] + sred[1][t][3]) + (sred[2][t][3] + sred[3][t][3]);
        const float rs = 1.0f / S;
        rscale[r0 + t] = rs;
        out_flow[(r0 + t) * 3 + 0] = CX * rs - pos0[(r0 + t) * 3 + 0];
        out_flow[(r0 + t) * 3 + 1] = CY * rs - pos0[(r0 + t) * 3 + 1];
        out_flow[(r0 + t) * 3 + 2] = CZ * rs - pos0[(r0 + t) * 3 + 2];
    }
}

// ---------------- Kernel B: one-wave-per-row MFMA splat, barrier-free ------
__global__ __launch_bounds__(256, 4) void splat_mfma_kernel(
    const unsigned short* __restrict__ probs_bf, const float* __restrict__ rscale,
    const float* __restrict__ pos0, const float4* __restrict__ pos1p,
    float* __restrict__ out_grid)
{
    const int t    = threadIdx.x;
    const int lane = t & 63;
    const int w    = t >> 6;
    const int r    = blockIdx.x * 4 + w;     // one row per wave
    const int b    = r >> 11;

    __shared__ __align__(16) short sAll[4][4608];   // per wave: sR 4096 + sZ 512
    char* sR = (char*)sAll[w];
    char* sZ = (char*)sAll[w] + 8192;

    const float inv = 1.0f / 0.12f;
    const float p0x = pos0[r * 3 + 0];
    const float p0y = pos0[r * 3 + 1];
    const float p0z = pos0[r * 3 + 2];
    const float4* p1p = pos1p + (size_t)b * L1V;
    const unsigned short* prow = probs_bf + (size_t)r * L1V;

    // per-row constants: coord = fma(p1, inv, k); window base from p1 >= -0.3
    const float kx = (0.72f - p0x) * inv - 0.5f;
    const float ky = (0.72f - p0y) * inv - 0.5f;
    const float kz = (0.72f - p0z) * inv - 0.5f;
    const int mnx = (int)floorf(-0.3f * inv + kx);
    const int mny = (int)floorf(-0.3f * inv + ky);
    const int mnz = (int)floorf(-0.3f * inv + kz);

    // zero this wave's slab: 9216B = 9 x b128 per lane
    {
        const short8 z8 = {0, 0, 0, 0, 0, 0, 0, 0};
        #pragma unroll
        for (int j = 0; j < 9; ++j)
            *(short8*)(sR + lane * 16 + j * 1024) = z8;
    }

    const int l15  = lane & 15;
    const int q16  = (lane >> 4) * 16;
    const int asw2 = (l15 & 7) << 4;
    const int aoff0 = l15 * 128 + ((0  + q16) ^ asw2);
    const int aoff1 = l15 * 128 + ((64 + q16) ^ asw2);
    const int zrow = l15 & 7;
    const int bsw2 = zrow << 4;
    const int boff0 = zrow * 128 + ((0  + q16) ^ bsw2);
    const int boff1 = zrow * 128 + ((64 + q16) ^ bsw2);
    const int lane2 = lane * 2;

    f32x4 acc[4];
    #pragma unroll
    for (int mt = 0; mt < 4; ++mt) acc[mt] = (f32x4){0.f, 0.f, 0.f, 0.f};

    char *P0 = sR + lane2, *P1 = sR + lane2, *P2 = sR + lane2,
         *P3 = sR + lane2, *P4 = sZ + lane2, *P5 = sZ + lane2;

    float4 pc = p1p[lane];
    float  pv = bf2f(prow[lane]);

    asm volatile("s_waitcnt lgkmcnt(0)" ::: "memory");   // slab zeroed (once)

    for (int ch = 0; ch < 16; ++ch) {
        float4 nc = pc;
        float  nv = pv;
        if (ch < 15) {
            const int nk = (ch + 1) * 64 + lane;
            nc = p1p[nk];
            nv = bf2f(prow[nk]);
        }

        const float ax = fmaf(pc.x, inv, kx);
        const float ay = fmaf(pc.y, inv, ky);
        const float az = fmaf(pc.z, inv, kz);
        const float fxf = floorf(ax), fyf = floorf(ay), fzf = floorf(az);
        const float fx = ax - fxf, fy = ay - fyf, fz = az - fzf;
        const int rix = (int)fxf - mnx;          // 0..6
        const int riy = (int)fyf - mny;
        const int riz = (int)fzf - mnz;
        const float wx0 = 1.f - fx, wy0 = 1.f - fy, wz0 = 1.f - fz;
        const float a0p = pv * wx0, a1p = pv * fx;
        const unsigned short r00 = f2bf(a0p * wy0), r01 = f2bf(a0p * fy);
        const unsigned short r10 = f2bf(a1p * wy0), r11 = f2bf(a1p * fy);
        const unsigned short z0 = f2bf(wz0), z1 = f2bf(fz);

        const int c00 = rix * 8 + riy;
        char* A0 = sR + (c00    ) * 128 + (lane2 ^ (((c00    ) & 7) << 4));
        char* A1 = sR + (c00 + 1) * 128 + (lane2 ^ (((c00 + 1) & 7) << 4));
        char* A2 = sR + (c00 + 8) * 128 + (lane2 ^ (((c00 + 8) & 7) << 4));
        char* A3 = sR + (c00 + 9) * 128 + (lane2 ^ (((c00 + 9) & 7) << 4));
        char* Z0a = sZ + riz * 128 + (lane2 ^ (riz << 4));
        char* Z1a = sZ + (riz + 1) * 128 + (lane2 ^ ((riz + 1) << 4));

        // rezero previous chunk's slots, then stage (in-order DS pipe)
        *(short*)P0 = 0; *(short*)P1 = 0; *(short*)P2 = 0;
        *(short*)P3 = 0; *(short*)P4 = 0; *(short*)P5 = 0;
        *(short*)A0 = (short)r00; *(short*)A1 = (short)r01;
        *(short*)A2 = (short)r10; *(short*)A3 = (short)r11;
        *(short*)Z0a = (short)z0; *(short*)Z1a = (short)z1;

        const short8 b0 = *(const short8*)(sZ + boff0);
        const short8 b1 = *(const short8*)(sZ + boff1);
        #pragma unroll
        for (int mt = 0; mt < 4; ++mt) {
            const short8 a0 = *(const short8*)(sR + mt * 2048 + aoff0);
            const short8 a1 = *(const short8*)(sR + mt * 2048 + aoff1);
            acc[mt] = __builtin_amdgcn_mfma_f32_16x16x32_bf16(a0, b0, acc[mt], 0, 0, 0);
            acc[mt] = __builtin_amdgcn_mfma_f32_16x16x32_bf16(a1, b1, acc[mt], 0, 0, 0);
        }

        P0 = A0; P1 = A1; P2 = A2; P3 = A3; P4 = Z0a; P5 = Z1a;
        pc = nc; pv = nv;
    }

    // ---- writeout: coalesced zero-fill, then masked scatter from acc ----
    const float rs = rscale[r];
    float* og = out_grid + (size_t)r * G3;
    {
        const float4 z4 = {0.f, 0.f, 0.f, 0.f};
        float4* og4 = (float4*)og;
        #pragma unroll
        for (int j = 0; j < 6; ++j) og4[j * 64 + lane] = z4;
        if (lane < 48) og4[384 + lane] = z4;
    }
    asm volatile("s_waitcnt vmcnt(0)" ::: "memory");

    const int zB = lane & 15;
    if (zB < 8) {
        const int gz = mnz + zB;
        if (gz <= 11) {
            const int h4 = (lane >> 4) * 4;
            const int rxm = 11 - mnx;
            const int rym = 11 - mny;
            float* base2 = og + mnx * 144 + mny * 12 + gz;
            #pragma unroll
            for (int mt = 0; mt < 4; ++mt) {
                #pragma unroll
                for (int rg = 0; rg < 4; ++rg) {
                    const int c  = mt * 16 + h4 + rg;
                    const int rx = c >> 3;
                    const int ry = c & 7;
                    if (rx <= rxm && ry <= rym)
                        base2[rx * 144 + ry * 12] = acc[mt][rg] * rs;
                }
            }
        }
    }
}

extern "C" void kernel_launch(void* const* d_in, const int* in_sizes, int n_in,
                              void* d_out, int out_size, void* d_ws, size_t ws_size,
                              hipStream_t stream) {
    const float* x0   = (const float*)d_in[0];
    const float* x1   = (const float*)d_in[1];
    const float* pos0 = (const float*)d_in[2];
    const float* pos1 = (const float*)d_in[3];
    float* out = (float*)d_out;

    const int B    = in_sizes[0] / (L0V * CV);   // 4
    const int rows = B * L0V;                    // 8192

    float* out_flow = out;
    float* out_grid = out + (size_t)rows * 3;

    // ws layout: probs_bf (16.78MB) | rscale (32KB) | ximg (512KB) | pos1p (64KB)
    unsigned short* probs_bf = (unsigned short*)d_ws;
    float* rscale = (float*)((char*)d_ws + (size_t)rows * L1V * sizeof(unsigned short));
    unsigned short* ximg = (unsigned short*)((char*)rscale + (size_t)rows * sizeof(float));
    float4* pos1p = (float4*)((char*)ximg + (size_t)B * 16 * 8192);

    const int nkeys = B * L1V;
    cvt_kernel<<<(B * L1V * CV / 8) / 256, 256, 0, stream>>>(
        x1, pos1, ximg, pos1p, nkeys);
    corr_probs_kernel<<<rows / RT, 256, 0, stream>>>(
        x0, ximg, pos0, pos1, out_flow, probs_bf, rscale);
    splat_mfma_kernel<<<rows / 4, 256, 0, stream>>>(
        probs_bf, rscale, pos0, pos1p, out_grid);
}